// Round 3
// baseline (415.293 us; speedup 1.0000x reference)
//
#include <hip/hip_runtime.h>
#include <hip/hip_bf16.h>

#define B_ 4
#define T_ 2048
#define C_ 1024
#define H_ 16
#define D_ 64
#define N3_ 3072
#define M_ (B_*T_)

typedef __bf16 bf16x8 __attribute__((ext_vector_type(8)));
typedef float f32x4 __attribute__((ext_vector_type(4)));

__device__ __forceinline__ unsigned short f2bf(float f){
  __bf16 h = (__bf16)f;              // RNE fptrunc -> v_cvt on gfx950
  return __builtin_bit_cast(unsigned short, h);
}
__device__ __forceinline__ unsigned int pk2(float a, float b){
  return (unsigned int)f2bf(a) | ((unsigned int)f2bf(b)<<16);
}

// ---------------- x fp32 -> bf16 one-time convert ---------------------------
__global__ __launch_bounds__(256) void x_cvt(
    const float* __restrict__ X, unsigned short* __restrict__ Xb)
{
  const size_t i = ((size_t)blockIdx.x*256 + threadIdx.x)*8;
  float4 f0 = *(const float4*)(X+i);
  float4 f1 = *(const float4*)(X+i+4);
  uint4 w = make_uint4(pk2(f0.x,f0.y), pk2(f0.z,f0.w), pk2(f1.x,f1.y), pk2(f1.z,f1.w));
  *(uint4*)(Xb+i) = w;
}

// ---------------- transpose + fp32->bf16 convert: src[K][N] -> dst[N][K] ----
__global__ __launch_bounds__(256) void transpose_cvt(
    const float* __restrict__ src, unsigned short* __restrict__ dst, int K, int N)
{
  __shared__ float tile[32][33];
  const int tx = threadIdx.x & 31, ty = threadIdx.x >> 5; // 32 x 8
  const int nt = blockIdx.x * 32, kt = blockIdx.y * 32;
  #pragma unroll
  for (int i=0;i<32;i+=8) tile[ty+i][tx] = src[(size_t)(kt+ty+i)*N + nt+tx];
  __syncthreads();
  #pragma unroll
  for (int i=0;i<32;i+=8) dst[(size_t)(nt+ty+i)*K + kt+tx] = f2bf(tile[tx][ty+i]);
}

// ---------------- QKV GEMM: Xb[M,1024]bf16 x Wt[3072,1024]^T ---------------
// Q (pre-scaled by 0.125*log2e), K -> [B,H,T,D] ; V -> [B,H,D,T]
__global__ __launch_bounds__(256) void qkv_gemm(
    const unsigned short* __restrict__ Xb, const unsigned short* __restrict__ Wt,
    const float* __restrict__ bias,
    unsigned short* __restrict__ Qb, unsigned short* __restrict__ Kb,
    unsigned short* __restrict__ Vt)
{
  __shared__ __align__(16) unsigned short As[128][40];
  __shared__ __align__(16) unsigned short Bs[128][40];
  const int tid = threadIdx.x;
  const int m0 = blockIdx.y*128, n0 = blockIdx.x*128;
  const int wv = tid>>6, lane = tid&63, lm = lane&15, lq = lane>>4;
  const int wr = wv>>1, wc = wv&1;
  f32x4 acc[4][4] = {};
  const int srow = tid>>1, skh = (tid&1)*16;
  for (int k0=0;k0<C_;k0+=32){
    __syncthreads();
    {
      const unsigned short* asrc = Xb + (size_t)(m0+srow)*C_ + k0 + skh;
      uint4 a0 = ((const uint4*)asrc)[0];
      uint4 a1 = ((const uint4*)asrc)[1];
      *(uint4*)&As[srow][skh]   = a0;
      *(uint4*)&As[srow][skh+8] = a1;
      const unsigned short* bsrc = Wt + (size_t)(n0+srow)*C_ + k0 + skh;
      uint4 b0 = ((const uint4*)bsrc)[0];
      uint4 b1 = ((const uint4*)bsrc)[1];
      *(uint4*)&Bs[srow][skh]   = b0;
      *(uint4*)&Bs[srow][skh+8] = b1;
    }
    __syncthreads();
    bf16x8 a[4], b[4];
    #pragma unroll
    for (int mt=0;mt<4;mt++) a[mt] = *(const bf16x8*)&As[wr*64+mt*16+lm][lq*8];
    #pragma unroll
    for (int nt=0;nt<4;nt++) b[nt] = *(const bf16x8*)&Bs[wc*64+nt*16+lm][lq*8];
    #pragma unroll
    for (int mt=0;mt<4;mt++)
      #pragma unroll
      for (int nt=0;nt<4;nt++)
        acc[mt][nt] = __builtin_amdgcn_mfma_f32_16x16x32_bf16(a[mt], b[nt], acc[mt][nt], 0,0,0);
  }
  // epilogue: C/D layout col=lane&15, row=(lane>>4)*4+r
  const int sel = n0>>10;  // block-uniform: 0=Q,1=K,2=V
  const float qsc = (sel==0) ? 0.18033688f : 1.0f;  // 0.125*log2(e) folded into Q
  #pragma unroll
  for (int mt=0;mt<4;mt++){
    const int grow = m0 + wr*64 + mt*16 + lq*4;
    const int bb = grow>>11, tt0 = grow&2047;
    #pragma unroll
    for (int nt=0;nt<4;nt++){
      const int gcol = n0 + wc*64 + nt*16 + lm;
      const int hh = (gcol>>6)&15, dd = gcol&63;
      const float bv = bias[gcol];
      if (sel==2){
        ushort4 pv;
        pv.x = f2bf(acc[mt][nt][0] + bv);
        pv.y = f2bf(acc[mt][nt][1] + bv);
        pv.z = f2bf(acc[mt][nt][2] + bv);
        pv.w = f2bf(acc[mt][nt][3] + bv);
        *(ushort4*)&Vt[ ((size_t)(bb*H_+hh)*D_ + dd)*T_ + tt0 ] = pv;
      } else {
        unsigned short* dst = (sel==0) ? Qb : Kb;
        #pragma unroll
        for (int r=0;r<4;r++)
          dst[ ((size_t)(bb*H_+hh)*T_ + tt0 + r)*D_ + dd ] = f2bf((acc[mt][nt][r] + bv)*qsc);
      }
    }
  }
}

// ---------------- flash attention: paired q-tiles, uniform 33 computes ------
// block bx handles q-tiles qiH=31-bx and qiL=bx; K/V staged once serve both.
// P has dedicated buffers -> P write/read is within-wave -> 2 barriers/iter.
__global__ __launch_bounds__(256, 4) void flash_attn(
    const unsigned short* __restrict__ Qb, const unsigned short* __restrict__ Kb,
    const unsigned short* __restrict__ Vt, unsigned short* __restrict__ Yb)
{
  __shared__ __align__(16) unsigned short Ks[64][72];
  __shared__ __align__(16) unsigned short Vs[64][72];
  __shared__ __align__(16) unsigned short PH[64][72];
  __shared__ __align__(16) unsigned short PL[64][72];
  const int tid = threadIdx.x;
  const int wv = tid>>6, lane = tid&63, lm = lane&15, lq = lane>>4;
  const int bh = blockIdx.y;
  const int qiH = 31 - (int)blockIdx.x;
  const int qiL = (int)blockIdx.x;
  const unsigned short* Qh = Qb + (size_t)bh*T_*D_;
  const unsigned short* Kh = Kb + (size_t)bh*T_*D_;
  const unsigned short* Vh = Vt + (size_t)bh*D_*T_;
  bf16x8 aqH[2], aqL[2];
  {
    const int qH = qiH*64 + wv*16 + lm;
    const int qL = qiL*64 + wv*16 + lm;
    aqH[0] = *(const bf16x8*)&Qh[(size_t)qH*D_ + lq*8];
    aqH[1] = *(const bf16x8*)&Qh[(size_t)qH*D_ + 32 + lq*8];
    aqL[0] = *(const bf16x8*)&Qh[(size_t)qL*D_ + lq*8];
    aqL[1] = *(const bf16x8*)&Qh[(size_t)qL*D_ + 32 + lq*8];
  }
  f32x4 oH[4] = {}, oL[4] = {};
  float lH[4] = {0.f,0.f,0.f,0.f}, lL[4] = {0.f,0.f,0.f,0.f};
  const int srow = tid>>2, sdh = (tid&3)*16;
  const unsigned short* kbase = Kh + (size_t)srow*D_ + sdh;
  const unsigned short* vbase = Vh + (size_t)srow*T_ + sdh;
  uint4 kr0 = ((const uint4*)kbase)[0];
  uint4 kr1 = ((const uint4*)kbase)[1];
  uint4 vr0 = ((const uint4*)vbase)[0];
  uint4 vr1 = ((const uint4*)vbase)[1];
  for (int j=0;j<=qiH;j++){
    __syncthreads();                       // prev PV reads of Ks/Vs done
    *(uint4*)&Ks[srow][sdh]   = kr0;
    *(uint4*)&Ks[srow][sdh+8] = kr1;
    *(uint4*)&Vs[srow][sdh]   = vr0;
    *(uint4*)&Vs[srow][sdh+8] = vr1;
    __syncthreads();                       // staging visible
    if (j < qiH){                          // prefetch next tile into VGPRs
      const unsigned short* kp = kbase + (size_t)(j+1)*64*D_;
      const unsigned short* vp = vbase + (size_t)(j+1)*64;
      kr0 = ((const uint4*)kp)[0]; kr1 = ((const uint4*)kp)[1];
      vr0 = ((const uint4*)vp)[0]; vr1 = ((const uint4*)vp)[1];
    }
    const bool doL = (j <= qiL);
    f32x4 sH[4] = {}, sL[4] = {};
    #pragma unroll
    for (int nt=0;nt<4;nt++){
      bf16x8 bk0 = *(const bf16x8*)&Ks[nt*16+lm][lq*8];
      bf16x8 bk1 = *(const bf16x8*)&Ks[nt*16+lm][32+lq*8];
      sH[nt] = __builtin_amdgcn_mfma_f32_16x16x32_bf16(aqH[0], bk0, sH[nt], 0,0,0);
      sH[nt] = __builtin_amdgcn_mfma_f32_16x16x32_bf16(aqH[1], bk1, sH[nt], 0,0,0);
      if (doL){
        sL[nt] = __builtin_amdgcn_mfma_f32_16x16x32_bf16(aqL[0], bk0, sL[nt], 0,0,0);
        sL[nt] = __builtin_amdgcn_mfma_f32_16x16x32_bf16(aqL[1], bk1, sL[nt], 0,0,0);
      }
    }
    // exp (Q pre-scaled so p = exp2(s)); mask only on the diagonal tile
    const int qrow0 = wv*16 + lq*4;
    if (j == qiH){
      #pragma unroll
      for (int nt=0;nt<4;nt++){
        const int col = nt*16+lm;
        #pragma unroll
        for (int r=0;r<4;r++)
          sH[nt][r] = (col <= qrow0+r) ? exp2f(sH[nt][r]) : 0.f;
      }
    } else {
      #pragma unroll
      for (int nt=0;nt<4;nt++)
        #pragma unroll
        for (int r=0;r<4;r++)
          sH[nt][r] = exp2f(sH[nt][r]);
    }
    #pragma unroll
    for (int r=0;r<4;r++)
      lH[r] += (sH[0][r]+sH[1][r]) + (sH[2][r]+sH[3][r]);
    #pragma unroll
    for (int nt=0;nt<4;nt++)
      #pragma unroll
      for (int r=0;r<4;r++)
        PH[wv*16 + lq*4 + r][nt*16+lm] = f2bf(sH[nt][r]);
    if (doL){
      if (j == qiL){
        #pragma unroll
        for (int nt=0;nt<4;nt++){
          const int col = nt*16+lm;
          #pragma unroll
          for (int r=0;r<4;r++)
            sL[nt][r] = (col <= qrow0+r) ? exp2f(sL[nt][r]) : 0.f;
        }
      } else {
        #pragma unroll
        for (int nt=0;nt<4;nt++)
          #pragma unroll
          for (int r=0;r<4;r++)
            sL[nt][r] = exp2f(sL[nt][r]);
      }
      #pragma unroll
      for (int r=0;r<4;r++)
        lL[r] += (sL[0][r]+sL[1][r]) + (sL[2][r]+sL[3][r]);
      #pragma unroll
      for (int nt=0;nt<4;nt++)
        #pragma unroll
        for (int r=0;r<4;r++)
          PL[wv*16 + lq*4 + r][nt*16+lm] = f2bf(sL[nt][r]);
    }
    // PV: P round-trip is within-wave (rows [16wv,16wv+16)) -> no barrier
    #pragma unroll
    for (int kc=0;kc<2;kc++){
      bf16x8 apH = *(const bf16x8*)&PH[wv*16+lm][kc*32+lq*8];
      bf16x8 apL = {};
      if (doL) apL = *(const bf16x8*)&PL[wv*16+lm][kc*32+lq*8];
      #pragma unroll
      for (int dt=0;dt<4;dt++){
        bf16x8 bv = *(const bf16x8*)&Vs[dt*16+lm][kc*32+lq*8];
        oH[dt] = __builtin_amdgcn_mfma_f32_16x16x32_bf16(apH, bv, oH[dt], 0,0,0);
        if (doL) oL[dt] = __builtin_amdgcn_mfma_f32_16x16x32_bf16(apL, bv, oL[dt], 0,0,0);
      }
    }
  }
  // final l: sum across the 16 lanes (lm) holding one row's 64 cols
  #pragma unroll
  for (int r=0;r<4;r++){
    float a = lH[r], b = lL[r];
    a += __shfl_xor(a,1); a += __shfl_xor(a,2); a += __shfl_xor(a,4); a += __shfl_xor(a,8);
    b += __shfl_xor(b,1); b += __shfl_xor(b,2); b += __shfl_xor(b,4); b += __shfl_xor(b,8);
    lH[r] = 1.0f/a; lL[r] = 1.0f/b;
  }
  const int bb = bh>>4, hh = bh&15;
  #pragma unroll
  for (int dt=0;dt<4;dt++)
    #pragma unroll
    for (int r=0;r<4;r++){
      const int qH = qiH*64 + wv*16 + lq*4 + r;
      const int qL = qiL*64 + wv*16 + lq*4 + r;
      Yb[ ((size_t)bb*T_ + qH)*C_ + hh*64 + dt*16 + lm ] = f2bf(oH[dt][r]*lH[r]);
      Yb[ ((size_t)bb*T_ + qL)*C_ + hh*64 + dt*16 + lm ] = f2bf(oL[dt][r]*lL[r]);
    }
}

// ---------------- proj GEMM: Y[M,1024](bf16) x Wpt[1024,1024]^T -> fp32 out -
__global__ __launch_bounds__(256) void proj_gemm(
    const unsigned short* __restrict__ Yb, const unsigned short* __restrict__ Wt,
    const float* __restrict__ bias, float* __restrict__ Out)
{
  __shared__ __align__(16) unsigned short As[128][40];
  __shared__ __align__(16) unsigned short Bs[128][40];
  const int tid = threadIdx.x;
  const int m0 = blockIdx.y*128, n0 = blockIdx.x*128;
  const int wv = tid>>6, lane = tid&63, lm = lane&15, lq = lane>>4;
  const int wr = wv>>1, wc = wv&1;
  f32x4 acc[4][4] = {};
  const int srow = tid>>1, skh = (tid&1)*16;
  for (int k0=0;k0<C_;k0+=32){
    __syncthreads();
    {
      const unsigned short* asrc = Yb + (size_t)(m0+srow)*C_ + k0 + skh;
      uint4 a0 = ((const uint4*)asrc)[0];
      uint4 a1 = ((const uint4*)asrc)[1];
      *(uint4*)&As[srow][skh]   = a0;
      *(uint4*)&As[srow][skh+8] = a1;
      const unsigned short* bsrc = Wt + (size_t)(n0+srow)*C_ + k0 + skh;
      uint4 b0 = ((const uint4*)bsrc)[0];
      uint4 b1 = ((const uint4*)bsrc)[1];
      *(uint4*)&Bs[srow][skh]   = b0;
      *(uint4*)&Bs[srow][skh+8] = b1;
    }
    __syncthreads();
    bf16x8 a[4], b[4];
    #pragma unroll
    for (int mt=0;mt<4;mt++) a[mt] = *(const bf16x8*)&As[wr*64+mt*16+lm][lq*8];
    #pragma unroll
    for (int nt=0;nt<4;nt++) b[nt] = *(const bf16x8*)&Bs[wc*64+nt*16+lm][lq*8];
    #pragma unroll
    for (int mt=0;mt<4;mt++)
      #pragma unroll
      for (int nt=0;nt<4;nt++)
        acc[mt][nt] = __builtin_amdgcn_mfma_f32_16x16x32_bf16(a[mt], b[nt], acc[mt][nt], 0,0,0);
  }
  #pragma unroll
  for (int mt=0;mt<4;mt++){
    const int grow = m0 + wr*64 + mt*16 + lq*4;
    #pragma unroll
    for (int nt=0;nt<4;nt++){
      const int gcol = n0 + wc*64 + nt*16 + lm;
      const float bv = bias[gcol];
      #pragma unroll
      for (int r=0;r<4;r++)
        Out[(size_t)(grow+r)*C_ + gcol] = acc[mt][nt][r] + bv;
    }
  }
}

extern "C" void kernel_launch(void* const* d_in, const int* in_sizes, int n_in,
                              void* d_out, int out_size, void* d_ws, size_t ws_size,
                              hipStream_t stream)
{
  const float* x      = (const float*)d_in[0];
  const float* W_attn = (const float*)d_in[1];
  const float* b_attn = (const float*)d_in[2];
  const float* W_proj = (const float*)d_in[3];
  const float* b_proj = (const float*)d_in[4];
  float* out = (float*)d_out;

  unsigned short* Wat = (unsigned short*)d_ws;            // [3072][1024] bf16
  unsigned short* Wpt = Wat + (size_t)N3_*C_;             // [1024][1024] bf16
  unsigned short* Xb  = Wpt + (size_t)C_*C_;              // [M,1024]  bf16
  unsigned short* Qb  = Xb  + (size_t)M_*C_;              // [B,H,T,D] bf16 (pre-scaled)
  unsigned short* Kb  = Qb  + (size_t)M_*C_;              // [B,H,T,D] bf16
  unsigned short* Vt  = Kb  + (size_t)M_*C_;              // [B,H,D,T] bf16
  unsigned short* Yb  = Vt  + (size_t)M_*C_;              // [M,1024]  bf16
  (void)ws_size; (void)in_sizes; (void)n_in; (void)out_size;

  x_cvt        <<<dim3(M_*C_/2048),      256, 0, stream>>>(x, Xb);
  transpose_cvt<<<dim3(N3_/32, C_/32),   256, 0, stream>>>(W_attn, Wat, C_, N3_);
  transpose_cvt<<<dim3(C_/32,  C_/32),   256, 0, stream>>>(W_proj, Wpt, C_, C_);
  qkv_gemm     <<<dim3(N3_/128, M_/128), 256, 0, stream>>>(Xb, Wat, b_attn, Qb, Kb, Vt);
  flash_attn   <<<dim3(16, B_*H_),       256, 0, stream>>>(Qb, Kb, Vt, Yb);
  proj_gemm    <<<dim3(C_/128, M_/128),  256, 0, stream>>>(Yb, Wpt, b_proj, out);
}

// Round 4
// 336.052 us; speedup vs baseline: 1.2358x; 1.2358x over previous
//
#include <hip/hip_runtime.h>
#include <hip/hip_bf16.h>

#define B_ 4
#define T_ 2048
#define C_ 1024
#define H_ 16
#define D_ 64
#define N3_ 3072
#define M_ (B_*T_)

typedef __bf16 bf16x8 __attribute__((ext_vector_type(8)));
typedef float f32x4 __attribute__((ext_vector_type(4)));

__device__ __forceinline__ unsigned short f2bf(float f){
  __bf16 h = (__bf16)f;              // RNE fptrunc -> v_cvt on gfx950
  return __builtin_bit_cast(unsigned short, h);
}
__device__ __forceinline__ unsigned int pk2(float a, float b){
  return (unsigned int)f2bf(a) | ((unsigned int)f2bf(b)<<16);
}
// async global->LDS, 16B per lane; LDS dest = base + lane*16 (wave-uniform base)
__device__ __forceinline__ void gload_lds16(const unsigned short* g, unsigned short* l){
  __builtin_amdgcn_global_load_lds(
      (const __attribute__((address_space(1))) void*)g,
      (__attribute__((address_space(3))) void*)l, 16, 0, 0);
}

// ---------------- x fp32 -> bf16 one-time convert ---------------------------
__global__ __launch_bounds__(256) void x_cvt(
    const float* __restrict__ X, unsigned short* __restrict__ Xb)
{
  const size_t i = ((size_t)blockIdx.x*256 + threadIdx.x)*8;
  float4 f0 = *(const float4*)(X+i);
  float4 f1 = *(const float4*)(X+i+4);
  uint4 w = make_uint4(pk2(f0.x,f0.y), pk2(f0.z,f0.w), pk2(f1.x,f1.y), pk2(f1.z,f1.w));
  *(uint4*)(Xb+i) = w;
}

// ---------------- transpose + fp32->bf16 convert: src[K][N] -> dst[N][K] ----
__global__ __launch_bounds__(256) void transpose_cvt(
    const float* __restrict__ src, unsigned short* __restrict__ dst, int K, int N)
{
  __shared__ float tile[32][33];
  const int tx = threadIdx.x & 31, ty = threadIdx.x >> 5; // 32 x 8
  const int nt = blockIdx.x * 32, kt = blockIdx.y * 32;
  #pragma unroll
  for (int i=0;i<32;i+=8) tile[ty+i][tx] = src[(size_t)(kt+ty+i)*N + nt+tx];
  __syncthreads();
  #pragma unroll
  for (int i=0;i<32;i+=8) dst[(size_t)(nt+ty+i)*K + kt+tx] = f2bf(tile[tx][ty+i]);
}

// ---------------- QKV GEMM (m97-style global_load_lds staging) --------------
// Xb[M,1024]bf16 x Wt[3072,1024]^T; Q pre-scaled by 0.125*log2e;
// Q,K -> [B,H,T,D]; V -> [B,H,D,T]
__global__ __launch_bounds__(256) void qkv_gemm(
    const unsigned short* __restrict__ Xb, const unsigned short* __restrict__ Wt,
    const float* __restrict__ bias,
    unsigned short* __restrict__ Qb, unsigned short* __restrict__ Kb,
    unsigned short* __restrict__ Vt)
{
  __shared__ __align__(16) unsigned short As[128][32]; // unpadded: required by global_load_lds
  __shared__ __align__(16) unsigned short Bs[128][32];
  const int tid = threadIdx.x;
  const int m0 = blockIdx.y*128, n0 = blockIdx.x*128;
  const int wv = tid>>6, lane = tid&63, lm = lane&15, lq = lane>>4;
  const int wr = wv>>1, wc = wv&1;
  f32x4 acc[4][4] = {};
  // staging: wave wv covers rows [wv*32, wv*32+32); lane -> row wv*32+(lane>>2),
  // 16B chunk (lane&3), XOR-swizzled source chunk key=(row>>1)&3=(lane>>3)&3
  const int schunk = (lane&3) ^ ((lane>>3)&3);
  const unsigned short* gA = Xb + (size_t)(m0 + wv*32 + (lane>>2))*C_ + schunk*8;
  const unsigned short* gB = Wt + (size_t)(n0 + wv*32 + (lane>>2))*C_ + schunk*8;
  unsigned short* lA0 = &As[wv*32][0];
  unsigned short* lA1 = &As[wv*32+16][0];
  unsigned short* lB0 = &Bs[wv*32][0];
  unsigned short* lB1 = &Bs[wv*32+16][0];
  const int rkey = (lm>>1)&3;      // frag-read swizzle key (row>>1)&3 with row=...+lm
  for (int k0=0;k0<C_;k0+=32){
    __syncthreads();
    gload_lds16(gA + k0,            lA0);
    gload_lds16(gA + 16*C_ + k0,    lA1);
    gload_lds16(gB + k0,            lB0);
    gload_lds16(gB + 16*C_ + k0,    lB1);
    __syncthreads();
    bf16x8 a[4], b[4];
    #pragma unroll
    for (int mt=0;mt<4;mt++) a[mt] = *(const bf16x8*)&As[wr*64+mt*16+lm][(lq^rkey)*8];
    #pragma unroll
    for (int nt=0;nt<4;nt++) b[nt] = *(const bf16x8*)&Bs[wc*64+nt*16+lm][(lq^rkey)*8];
    #pragma unroll
    for (int mt=0;mt<4;mt++)
      #pragma unroll
      for (int nt=0;nt<4;nt++)
        acc[mt][nt] = __builtin_amdgcn_mfma_f32_16x16x32_bf16(a[mt], b[nt], acc[mt][nt], 0,0,0);
  }
  // epilogue: C/D layout col=lane&15, row=(lane>>4)*4+r
  const int sel = n0>>10;  // block-uniform: 0=Q,1=K,2=V
  const float qsc = (sel==0) ? 0.18033688f : 1.0f;  // 0.125*log2(e) folded into Q
  #pragma unroll
  for (int mt=0;mt<4;mt++){
    const int grow = m0 + wr*64 + mt*16 + lq*4;
    const int bb = grow>>11, tt0 = grow&2047;
    #pragma unroll
    for (int nt=0;nt<4;nt++){
      const int gcol = n0 + wc*64 + nt*16 + lm;
      const int hh = (gcol>>6)&15, dd = gcol&63;
      const float bv = bias[gcol];
      if (sel==2){
        ushort4 pv;
        pv.x = f2bf(acc[mt][nt][0] + bv);
        pv.y = f2bf(acc[mt][nt][1] + bv);
        pv.z = f2bf(acc[mt][nt][2] + bv);
        pv.w = f2bf(acc[mt][nt][3] + bv);
        *(ushort4*)&Vt[ ((size_t)(bb*H_+hh)*D_ + dd)*T_ + tt0 ] = pv;
      } else {
        unsigned short* dst = (sel==0) ? Qb : Kb;
        #pragma unroll
        for (int r=0;r<4;r++)
          dst[ ((size_t)(bb*H_+hh)*T_ + tt0 + r)*D_ + dd ] = f2bf((acc[mt][nt][r] + bv)*qsc);
      }
    }
  }
}

// ---------------- flash attention (R2 structure + reg prefetch, 3 barriers) -
__global__ __launch_bounds__(256, 6) void flash_attn(
    const unsigned short* __restrict__ Qb, const unsigned short* __restrict__ Kb,
    const unsigned short* __restrict__ Vt, unsigned short* __restrict__ Yb)
{
  __shared__ __align__(16) unsigned short KPs[64][72]; // K tile; reused for P
  __shared__ __align__(16) unsigned short Vs[64][72];  // V^T tile [d][key]
  const int tid = threadIdx.x;
  const int wv = tid>>6, lane = tid&63, lm = lane&15, lq = lane>>4;
  const int bh = blockIdx.y;
  const int qi = (int)gridDim.x - 1 - (int)blockIdx.x;  // heavy blocks first
  const int qbase = qi*64;
  const unsigned short* Qh = Qb + (size_t)bh*T_*D_;
  const unsigned short* Kh = Kb + (size_t)bh*T_*D_;
  const unsigned short* Vh = Vt + (size_t)bh*D_*T_;
  bf16x8 aq[2];
  {
    const int q = qbase + wv*16 + lm;
    aq[0] = *(const bf16x8*)&Qh[(size_t)q*D_ + lq*8];
    aq[1] = *(const bf16x8*)&Qh[(size_t)q*D_ + 32 + lq*8];
  }
  f32x4 o[4] = {};
  float l_r[4] = {0.f,0.f,0.f,0.f};
  const int srow = tid>>2, sdh = (tid&3)*16;
  const unsigned short* kbase = Kh + (size_t)srow*D_ + sdh;
  const unsigned short* vbase = Vh + (size_t)srow*T_ + sdh;
  uint4 kr0 = ((const uint4*)kbase)[0];
  uint4 kr1 = ((const uint4*)kbase)[1];
  uint4 vr0 = ((const uint4*)vbase)[0];
  uint4 vr1 = ((const uint4*)vbase)[1];
  for (int j=0;j<=qi;j++){
    __syncthreads();                       // prev iter LDS reads done
    *(uint4*)&KPs[srow][sdh]   = kr0;
    *(uint4*)&KPs[srow][sdh+8] = kr1;
    *(uint4*)&Vs[srow][sdh]    = vr0;
    *(uint4*)&Vs[srow][sdh+8]  = vr1;
    __syncthreads();                       // staging visible
    if (j < qi){                           // prefetch next tile into VGPRs
      const unsigned short* kp = kbase + (size_t)(j+1)*64*D_;
      const unsigned short* vp = vbase + (size_t)(j+1)*64;
      kr0 = ((const uint4*)kp)[0]; kr1 = ((const uint4*)kp)[1];
      vr0 = ((const uint4*)vp)[0]; vr1 = ((const uint4*)vp)[1];
    }
    // S = Q K^T  (per wave: 16 q rows x 64 keys)
    f32x4 s[4] = {};
    #pragma unroll
    for (int nt=0;nt<4;nt++){
      bf16x8 bk0 = *(const bf16x8*)&KPs[nt*16+lm][lq*8];
      bf16x8 bk1 = *(const bf16x8*)&KPs[nt*16+lm][32+lq*8];
      s[nt] = __builtin_amdgcn_mfma_f32_16x16x32_bf16(aq[0], bk0, s[nt], 0,0,0);
      s[nt] = __builtin_amdgcn_mfma_f32_16x16x32_bf16(aq[1], bk1, s[nt], 0,0,0);
    }
    // p = exp2(s) (Q pre-scaled); causal mask only on diagonal tile
    if (j==qi){
      const int qrow0 = wv*16 + lq*4;
      #pragma unroll
      for (int nt=0;nt<4;nt++){
        const int col = nt*16+lm;
        #pragma unroll
        for (int r=0;r<4;r++)
          s[nt][r] = (col <= qrow0+r) ? exp2f(s[nt][r]) : 0.f;
      }
    } else {
      #pragma unroll
      for (int nt=0;nt<4;nt++)
        #pragma unroll
        for (int r=0;r<4;r++)
          s[nt][r] = exp2f(s[nt][r]);
    }
    #pragma unroll
    for (int r=0;r<4;r++)
      l_r[r] += (s[0][r]+s[1][r]) + (s[2][r]+s[3][r]);
    __syncthreads();                       // all QK^T reads of KPs done
    #pragma unroll
    for (int nt=0;nt<4;nt++)
      #pragma unroll
      for (int r=0;r<4;r++)
        KPs[wv*16 + lq*4 + r][nt*16+lm] = f2bf(s[nt][r]);  // C-layout -> LDS
    // no barrier: P rows [16wv,16wv+16) are written and read by wave wv only
    #pragma unroll
    for (int kc=0;kc<2;kc++){
      bf16x8 ap = *(const bf16x8*)&KPs[wv*16+lm][kc*32+lq*8];
      #pragma unroll
      for (int dt=0;dt<4;dt++){
        bf16x8 bv = *(const bf16x8*)&Vs[dt*16+lm][kc*32+lq*8];
        o[dt] = __builtin_amdgcn_mfma_f32_16x16x32_bf16(ap, bv, o[dt], 0,0,0);
      }
    }
  }
  // final l: sum across the 16 lanes (lm) holding one row's 64 cols
  #pragma unroll
  for (int r=0;r<4;r++){
    float rs = l_r[r];
    rs += __shfl_xor(rs,1); rs += __shfl_xor(rs,2);
    rs += __shfl_xor(rs,4); rs += __shfl_xor(rs,8);
    l_r[r] = 1.0f/rs;
  }
  const int bb = bh>>4, hh = bh&15;
  #pragma unroll
  for (int dt=0;dt<4;dt++)
    #pragma unroll
    for (int r=0;r<4;r++){
      const int q = qbase + wv*16 + lq*4 + r;
      Yb[ ((size_t)bb*T_ + q)*C_ + hh*64 + dt*16 + lm ] = f2bf(o[dt][r]*l_r[r]);
    }
}

// ---------------- proj GEMM (m97-style): Yb x Wpt^T -> fp32 out + bias ------
__global__ __launch_bounds__(256) void proj_gemm(
    const unsigned short* __restrict__ Yb, const unsigned short* __restrict__ Wt,
    const float* __restrict__ bias, float* __restrict__ Out)
{
  __shared__ __align__(16) unsigned short As[128][32];
  __shared__ __align__(16) unsigned short Bs[128][32];
  const int tid = threadIdx.x;
  const int m0 = blockIdx.y*128, n0 = blockIdx.x*128;
  const int wv = tid>>6, lane = tid&63, lm = lane&15, lq = lane>>4;
  const int wr = wv>>1, wc = wv&1;
  f32x4 acc[4][4] = {};
  const int schunk = (lane&3) ^ ((lane>>3)&3);
  const unsigned short* gA = Yb + (size_t)(m0 + wv*32 + (lane>>2))*C_ + schunk*8;
  const unsigned short* gB = Wt + (size_t)(n0 + wv*32 + (lane>>2))*C_ + schunk*8;
  unsigned short* lA0 = &As[wv*32][0];
  unsigned short* lA1 = &As[wv*32+16][0];
  unsigned short* lB0 = &Bs[wv*32][0];
  unsigned short* lB1 = &Bs[wv*32+16][0];
  const int rkey = (lm>>1)&3;
  for (int k0=0;k0<C_;k0+=32){
    __syncthreads();
    gload_lds16(gA + k0,            lA0);
    gload_lds16(gA + 16*C_ + k0,    lA1);
    gload_lds16(gB + k0,            lB0);
    gload_lds16(gB + 16*C_ + k0,    lB1);
    __syncthreads();
    bf16x8 a[4], b[4];
    #pragma unroll
    for (int mt=0;mt<4;mt++) a[mt] = *(const bf16x8*)&As[wr*64+mt*16+lm][(lq^rkey)*8];
    #pragma unroll
    for (int nt=0;nt<4;nt++) b[nt] = *(const bf16x8*)&Bs[wc*64+nt*16+lm][(lq^rkey)*8];
    #pragma unroll
    for (int mt=0;mt<4;mt++)
      #pragma unroll
      for (int nt=0;nt<4;nt++)
        acc[mt][nt] = __builtin_amdgcn_mfma_f32_16x16x32_bf16(a[mt], b[nt], acc[mt][nt], 0,0,0);
  }
  #pragma unroll
  for (int mt=0;mt<4;mt++){
    const int grow = m0 + wr*64 + mt*16 + lq*4;
    #pragma unroll
    for (int nt=0;nt<4;nt++){
      const int gcol = n0 + wc*64 + nt*16 + lm;
      const float bv = bias[gcol];
      #pragma unroll
      for (int r=0;r<4;r++)
        Out[(size_t)(grow+r)*C_ + gcol] = acc[mt][nt][r] + bv;
    }
  }
}

extern "C" void kernel_launch(void* const* d_in, const int* in_sizes, int n_in,
                              void* d_out, int out_size, void* d_ws, size_t ws_size,
                              hipStream_t stream)
{
  const float* x      = (const float*)d_in[0];
  const float* W_attn = (const float*)d_in[1];
  const float* b_attn = (const float*)d_in[2];
  const float* W_proj = (const float*)d_in[3];
  const float* b_proj = (const float*)d_in[4];
  float* out = (float*)d_out;

  unsigned short* Wat = (unsigned short*)d_ws;            // [3072][1024] bf16
  unsigned short* Wpt = Wat + (size_t)N3_*C_;             // [1024][1024] bf16
  unsigned short* Xb  = Wpt + (size_t)C_*C_;              // [M,1024]  bf16
  unsigned short* Qb  = Xb  + (size_t)M_*C_;              // [B,H,T,D] bf16 (pre-scaled)
  unsigned short* Kb  = Qb  + (size_t)M_*C_;              // [B,H,T,D] bf16
  unsigned short* Vt  = Kb  + (size_t)M_*C_;              // [B,H,D,T] bf16
  unsigned short* Yb  = Vt  + (size_t)M_*C_;              // [M,1024]  bf16
  (void)ws_size; (void)in_sizes; (void)n_in; (void)out_size;

  x_cvt        <<<dim3(M_*C_/2048),      256, 0, stream>>>(x, Xb);
  transpose_cvt<<<dim3(N3_/32, C_/32),   256, 0, stream>>>(W_attn, Wat, C_, N3_);
  transpose_cvt<<<dim3(C_/32,  C_/32),   256, 0, stream>>>(W_proj, Wpt, C_, C_);
  qkv_gemm     <<<dim3(N3_/128, M_/128), 256, 0, stream>>>(Xb, Wat, b_attn, Qb, Kb, Vt);
  flash_attn   <<<dim3(T_/64, B_*H_),    256, 0, stream>>>(Qb, Kb, Vt, Yb);
  proj_gemm    <<<dim3(C_/128, M_/128),  256, 0, stream>>>(Yb, Wpt, b_proj, out);
}